// Round 11
// baseline (4876.253 us; speedup 1.0000x reference)
//
#include <hip/hip_runtime.h>
#include <hip/hip_fp16.h>

#define TT 2048
typedef unsigned int uint32;
typedef unsigned long long uint64;
typedef unsigned short ushort;

typedef _Float16 half2v __attribute__((ext_vector_type(2)));

#if defined(__has_builtin)
#  if __has_builtin(__builtin_amdgcn_fdot2)
#    define HAVE_DOT2 1
#  endif
#endif
#ifndef HAVE_DOT2
#  define HAVE_DOT2 0
#endif

// ---- d_ws layout ----
// WREGH: uint32[2][176][512]    packed fp16 weight pairs    (720896 B)
// exS  : uint64[2][64][2][256]  {tag,f32} agent-safe        (524288 B)
// exF  : uint64[2][64][2][256]  {tag,f32} L2-fast (sc0)     (524288 B)
// PS   : uint32[512] pairing state                          (2048 B)
//        [0..7]=ticket/xcd [8]=arrivals [16..143]=probe [160..287]=vote
#define WREG_N (2 * 176 * 512)       // 180224 dwords
#define EX_N   (2 * 64 * 2 * 256)    // 65536 qwords per buffer
#define ZQ_N   (2 * EX_N + 256)      // qwords zeroed by prep (exS+exF+PS)

__device__ __forceinline__ float dot2(uint32 a, uint32 w, float c)
{
#if HAVE_DOT2
    return __builtin_amdgcn_fdot2(__builtin_bit_cast(half2v, a),
                                  __builtin_bit_cast(half2v, w), c, false);
#else
    half2v av = __builtin_bit_cast(half2v, a);
    half2v wv = __builtin_bit_cast(half2v, w);
    c = fmaf((float)av.x, (float)wv.x, c);
    return fmaf((float)av.y, (float)wv.y, c);
#endif
}

__device__ __forceinline__ uint32 pkh(float a, float b)
{
    __half ha = __float2half(a), hb = __float2half(b);
    ushort ua = *reinterpret_cast<ushort*>(&ha);
    ushort ub = *reinterpret_cast<ushort*>(&hb);
    return (uint32)ua | ((uint32)ub << 16);
}

// Member g's cat slice, k_slice in [0,448):
//  [0,256) -> x cols 256g+k ; [256,384) -> s cols 128g+(k-256) ; [384,448) -> I cols 64g+(k-384)
__device__ __forceinline__ float getSlice(const float* __restrict__ W_ih,
                                          const float* __restrict__ W_hh,
                                          int g, int j, int k)
{
    if (k < 256) return W_ih[j * 640 + 256 * g + k];
    if (k < 384) return W_hh[j * 256 + 128 * g + (k - 256)];
    return W_ih[j * 640 + 512 + 64 * g + (k - 384)];
}

// Per-thread weight layout: identical to round 10 (proven absmax 0.0039).
__global__ void prep_kernel(const float* __restrict__ W_ih,
                            const float* __restrict__ W_hh,
                            const float* __restrict__ W_out,
                            uint32* __restrict__ WREGH,
                            uint64* __restrict__ zbase)
{
    int idx = blockIdx.x * blockDim.x + threadIdx.x;
    if (idx < WREG_N) {
        int tid  = idx & 511;
        int q    = idx >> 9;       // g*176 + slot
        int g    = q / 176;
        int slot = q % 176;
        float lo, hi;
        if (slot < 112) {
            int j = tid >> 1, h = tid & 1;
            int k0 = 2 * (112 * h + slot);
            lo = getSlice(W_ih, W_hh, g, j, k0);
            hi = getSlice(W_ih, W_hh, g, j, k0 + 1);
        } else {
            int s  = slot - 112;
            int ii = s >> 2, m = s & 3;
            int nloc = tid >> 1, hh = tid & 1;
            int n  = 256 * g + nloc;
            int k0 = 128 * hh + 8 * ii + 2 * m;
            lo = W_out[n * 256 + k0];
            hi = W_out[n * 256 + k0 + 1];
        }
        WREGH[idx] = pkh(lo, hi);
    } else if (idx < WREG_N + ZQ_N) {
        zbase[idx - WREG_N] = 0ULL;   // exchange tags + pairing state start 0
    }
}

// LDS-only barrier: does NOT drain vmcnt (global ops stay in flight).
__device__ __forceinline__ void bar_lds()
{
    asm volatile("s_waitcnt lgkmcnt(0)" ::: "memory");
    __builtin_amdgcn_s_barrier();
    asm volatile("" ::: "memory");
}

__device__ __forceinline__ void st64_sc0(uint64* p, uint64 v)
{
    asm volatile("global_store_dwordx2 %0, %1, off sc0" :: "v"(p), "v"(v) : "memory");
}
__device__ __forceinline__ uint64 ld64_sc0(const uint64* p)
{
    uint64 r;
    asm volatile("global_load_dwordx2 %0, %1, off sc0\n\ts_waitcnt vmcnt(0)"
                 : "=v"(r) : "v"(p) : "memory");
    return r;
}
__device__ __forceinline__ void st32_sc0(uint32* p, uint32 v)
{
    asm volatile("global_store_dword %0, %1, off sc0" :: "v"(p), "v"(v) : "memory");
}
__device__ __forceinline__ uint32 ld32_sc0(const uint32* p)
{
    uint32 r;
    asm volatile("global_load_dword %0, %1, off sc0\n\ts_waitcnt vmcnt(0)"
                 : "=v"(r) : "v"(p) : "memory");
    return r;
}

__global__ __launch_bounds__(512, 2)
void scan_kernel(const float* __restrict__ I,
                 const float* __restrict__ b_ih, const float* __restrict__ b_hh,
                 const float* __restrict__ b_out, const float* __restrict__ A,
                 const uint32* __restrict__ WREGH,
                 uint64* exS, uint64* exF, uint32* PS,
                 float* __restrict__ out)
{
    __shared__ uint4 apk4[2][56];     // member-slice act, fp16 pairs, dbuf
    __shared__ uint4 s4pk[32];        // FULL s (256 vals) packed pairs
    __shared__ float xf32[256];       // exact f32 x state (own n-half)
    __shared__ uint32 shInfo[2];      // {e | g<<16, fastpair}

    const int tid = threadIdx.x;

    // ---------- dynamic same-XCD pairing + sc0-channel validation ----------
    if (tid == 0) {
        uint32 x;
        asm volatile("s_getreg_b32 %0, hwreg(HW_REG_XCC_ID)" : "=s"(x));
        x &= 7u;   // clamp: garbage reads degrade to fallback, never fault
        uint32 rank = __hip_atomic_fetch_add(PS + x, 1u,
                          __ATOMIC_RELAXED, __HIP_MEMORY_SCOPE_AGENT);
        __hip_atomic_fetch_add(PS + 8, 1u, __ATOMIC_RELAXED, __HIP_MEMORY_SCOPE_AGENT);
        // all 128 WGs are co-resident; every WG adds unconditionally -> live wait
        while (__hip_atomic_load(PS + 8, __ATOMIC_RELAXED, __HIP_MEMORY_SCOPE_AGENT) < 128u)
            __builtin_amdgcn_s_sleep(1);
        uint32 cnt[8];
        #pragma unroll
        for (int i = 0; i < 8; ++i)
            cnt[i] = __hip_atomic_load(PS + i, __ATOMIC_RELAXED, __HIP_MEMORY_SCOPE_AGENT);
        uint32 totp = 0, cumB = 0, sB = 0;
        #pragma unroll
        for (int i = 0; i < 8; ++i) {
            if ((uint32)i < x) { cumB += cnt[i] >> 1; sB += cnt[i] & 1; }
            totp += cnt[i] >> 1;
        }
        uint32 e, g;
        if (rank < 2u * (cnt[x] >> 1)) { e = cumB + (rank >> 1); g = rank & 1u; }
        else                           { e = totp + (sB >> 1);   g = sB & 1u; }
        // bounded sc0 probe of THIS pair's channel; vote on the live agent channel
        uint32* pb = PS + 16  + 2 * e;
        uint32* vt = PS + 160 + 2 * e;
        const uint32 TOK = 0x5EEDF00Du;
        st32_sc0(pb + g, TOK);
        uint32 seen = 0;
        for (int it = 0; it < 4096 && !seen; ++it)
            seen = (ld32_sc0(pb + (1u - g)) == TOK) ? 1u : 0u;
        __hip_atomic_store(vt + g, seen ? 2u : 1u,
                           __ATOMIC_RELAXED, __HIP_MEMORY_SCOPE_AGENT);
        uint32 v0, v1;
        do {
            v0 = __hip_atomic_load(vt + 0, __ATOMIC_RELAXED, __HIP_MEMORY_SCOPE_AGENT);
            v1 = __hip_atomic_load(vt + 1, __ATOMIC_RELAXED, __HIP_MEMORY_SCOPE_AGENT);
        } while (v0 == 0u || v1 == 0u);
        shInfo[0] = e | (g << 16);
        shInfo[1] = (v0 == 2u && v1 == 2u) ? 1u : 0u;
    }
    __syncthreads();
    const int  e        = shInfo[0] & 0xffff;
    const int  g        = shInfo[0] >> 16;
    const bool fastpair = (shInfo[1] != 0);
    bool fastok = fastpair;            // sticky per-thread poll-side switch

    // ---- weights -> VGPR (static-indexed, fully unrolled, pinned) ----
    uint32 wA[112], wB[64];
    const uint32* wsrc = WREGH + (size_t)g * (176 * 512) + tid;
    #pragma unroll
    for (int i = 0; i < 112; ++i) { wA[i] = wsrc[(size_t)i * 512]; asm("" : "+v"(wA[i])); }
    #pragma unroll
    for (int i = 0; i < 64;  ++i) { wB[i] = wsrc[(size_t)(112 + i) * 512]; asm("" : "+v"(wB[i])); }

    const int h    = tid & 1;     // A k-half within lane pair (224 k each)
    const int jA   = tid >> 1;    // A output row [0,256)
    const int hh   = tid & 1;     // B k-half (128 k each)
    const int nloc = tid >> 1;    // B output row within member half

    const float bs   = ((tid & 1) == 0) ? (b_ih[jA] + b_hh[jA]) : 0.f;
    const float bo_r = ((tid & 1) == 0) ? b_out[256 * g + nloc] : 0.f;
    const float Av_r = ((tid & 1) == 0) ? A[256 * g + nloc] : 0.f;

    const size_t iBase   = (size_t)e * TT * 128 + 64 * g;
    const size_t outBase = (size_t)e * TT * 512 + 256 * g;

    {   // init buffer 0: x=0 (pairs 0..127), s=0 (128..191), I(0) (192..223)
        uint32* a0p = (uint32*)&apk4[0][0];
        if (tid < 192) a0p[tid] = 0u;
        else if (tid < 224) {
            int m = tid - 192;
            a0p[tid] = pkh(I[iBase + 2 * m], I[iBase + 2 * m + 1]);
        }
        if (tid < 256) xf32[tid] = 0.f;
    }
    __syncthreads();

    for (int t = 0; t < TT; ++t) {
        const int par = t & 1;
        const uint4* rdp = apk4[par];
        uint32*      wrp = (uint32*)apk4[par ^ 1];

        // I(t+1): issue loads early (hides HBM under compute + sync)
        float2 iv2 = make_float2(0.f, 0.f);
        if (tid < 32) {
            int tl = (t + 1 < TT) ? (t + 1) : t;
            iv2 = *(const float2*)(I + iBase + (size_t)tl * 128 + 2 * tid);
        }

        // ---- phase A: pre[jA] partial over this member's 448-k slice ----
        float a0 = 0.f, a1 = 0.f;
        #pragma unroll
        for (int i = 0; i < 28; ++i) {
            uint4 av = rdp[28 * h + i];      // 2 addrs/wave -> LDS broadcast
            a0 = dot2(av.x, wA[4 * i + 0], a0);
            a1 = dot2(av.y, wA[4 * i + 1], a1);
            a0 = dot2(av.z, wA[4 * i + 2], a0);
            a1 = dot2(av.w, wA[4 * i + 3], a1);
        }
        float acc = a0 + a1;
        acc += __shfl_xor(acc, 1);           // h0 + h1 -> full slice partial

        const uint32 tgt   = (uint32)(t + 1);
        const size_t exoff = (size_t)(par * 64 + e) * (2 * 256);

        float sn = 0.f;
        if ((tid & 1) == 0) {
            uint64 u = ((uint64)tgt << 32) | (uint64)__float_as_uint(acc);
            // dup-store: fast (shared L2) if pair validated; agent copy ALWAYS
            // (liveness for any reader that has fallen back)
            if (fastpair) st64_sc0(exF + exoff + g * 256 + jA, u);
            __hip_atomic_store(exS + exoff + g * 256 + jA, u,
                               __ATOMIC_RELAXED, __HIP_MEMORY_SCOPE_AGENT);

            const uint64* fp = exF + exoff + (1 - g) * 256 + jA;
            const uint64* sp = exS + exoff + (1 - g) * 256 + jA;
            uint64 up = 0; bool got = false;
            if (fastok) {                    // bounded L2 poll; sticky fallback
                for (int it = 0; it < 1024 && !got; ++it) {
                    up = ld64_sc0(fp);
                    got = ((uint32)(up >> 32) == tgt);
                }
                if (!got) fastok = false;
            }
            while (!got) {                   // proven-live agent channel
                up = __hip_atomic_load(sp, __ATOMIC_RELAXED, __HIP_MEMORY_SCOPE_AGENT);
                got = ((uint32)(up >> 32) == tgt);
            }

            float pre = acc + bs + __uint_as_float((uint32)up);  // fixed order
            // tanh(x) = 1 - 2/(exp(2x)+1): exact identity, branch-free
            float ex2 = __expf(2.f * pre);
            sn = 1.f - 2.f / (ex2 + 1.f);
        }
        {   // pack s pairs: threads 4m (jA=2m) and 4m+2 (jA=2m+1)
            float sno = __shfl_xor(sn, 2);
            if ((tid & 3) == 0) {
                int p = tid >> 2;                    // full-s pair index [0,128)
                uint32 sp2 = pkh(sn, sno);
                ((uint32*)s4pk)[p] = sp2;            // for phase B
                int d = p - 64 * g;                  // own s-half for next A
                if (d >= 0 && d < 64) wrp[128 + d] = sp2;
            }
        }
        bar_lds();                           // (1) s ready

        // ---- phase B: f[n], lane pair covers k=256 ----
        float c0 = 0.f, c1 = 0.f;
        #pragma unroll
        for (int i = 0; i < 16; ++i) {
            uint4 sv = s4pk[16 * hh + i];    // 2 addrs/wave -> LDS broadcast
            c0 = dot2(sv.x, wB[4 * i + 0], c0);
            c1 = dot2(sv.y, wB[4 * i + 1], c1);
            c0 = dot2(sv.z, wB[4 * i + 2], c0);
            c1 = dot2(sv.w, wB[4 * i + 3], c1);
        }
        float f = c0 + c1;
        f += __shfl_xor(f, 1);               // full k-sum at both pair lanes

        float xn = 0.f;
        if ((tid & 1) == 0) {
            float ff = fmaxf(f + bo_r, 0.f);
            float xo = xf32[nloc];           // exact f32 state in, f32 out
            xn = (xo + 0.1f * ff * Av_r) / (1.1f + 0.1f * ff);
            xf32[nloc] = xn;                 // same-thread RMW: no race
            out[outBase + (size_t)t * 512 + nloc] = xn;
        }
        {   // pack x pairs (fp16 copy feeds next A): threads 4m / 4m+2
            float xno = __shfl_xor(xn, 2);
            if ((tid & 3) == 0)
                wrp[tid >> 2] = pkh(xn, xno);
        }
        if (tid < 32) wrp[192 + tid] = pkh(iv2.x, iv2.y);   // stage I(t+1)
        bar_lds();                           // (2) state ready for next A
    }
}

extern "C" void kernel_launch(void* const* d_in, const int* in_sizes, int n_in,
                              void* d_out, int out_size, void* d_ws, size_t ws_size,
                              hipStream_t stream)
{
    const float* I     = (const float*)d_in[0];
    const float* W_ih  = (const float*)d_in[1];
    const float* W_hh  = (const float*)d_in[2];
    const float* b_ih  = (const float*)d_in[3];
    const float* b_hh  = (const float*)d_in[4];
    const float* W_out = (const float*)d_in[5];
    const float* b_out = (const float*)d_in[6];
    const float* A     = (const float*)d_in[7];

    uint32* WREGH = (uint32*)d_ws;
    uint64* zbase = (uint64*)((uint32*)d_ws + WREG_N);   // exS | exF | PS
    uint64* exS   = zbase;
    uint64* exF   = zbase + EX_N;
    uint32* PS    = (uint32*)(zbase + 2 * EX_N);

    const int total = WREG_N + ZQ_N;
    prep_kernel<<<(total + 1023) / 1024, 1024, 0, stream>>>(W_ih, W_hh, W_out,
                                                            WREGH, zbase);
    scan_kernel<<<128, 512, 0, stream>>>(I, b_ih, b_hh, b_out, A,
                                         WREGH, exS, exF, PS, (float*)d_out);
}

// Round 12
// 4577.710 us; speedup vs baseline: 1.0652x; 1.0652x over previous
//
#include <hip/hip_runtime.h>
#include <hip/hip_fp16.h>

#define TT 2048
typedef unsigned int uint32;
typedef unsigned long long uint64;
typedef unsigned short ushort;

typedef _Float16 half2v __attribute__((ext_vector_type(2)));

#if defined(__has_builtin)
#  if __has_builtin(__builtin_amdgcn_fdot2)
#    define HAVE_DOT2 1
#  endif
#endif
#ifndef HAVE_DOT2
#  define HAVE_DOT2 0
#endif

// ---- d_ws layout ----
// WREGH: uint32[2][176][512]    packed fp16 weight pairs    (720896 B)
// exS  : uint64[2][64][2][256]  {tag,f32} agent-safe        (524288 B)
// exF  : uint64[2][64][2][256]  {tag,f32} L2-atomic fast    (524288 B)
// PS   : uint32[512] pairing state                          (2048 B)
//        [0..7]=ticket/xcd [8]=arrivals [16..143]=probe [160..287]=vote
#define WREG_N (2 * 176 * 512)       // 180224 dwords
#define EX_N   (2 * 64 * 2 * 256)    // 65536 qwords per buffer
#define ZQ_N   (2 * EX_N + 256)      // qwords zeroed by prep (exS+exF+PS)

__device__ __forceinline__ float dot2(uint32 a, uint32 w, float c)
{
#if HAVE_DOT2
    return __builtin_amdgcn_fdot2(__builtin_bit_cast(half2v, a),
                                  __builtin_bit_cast(half2v, w), c, false);
#else
    half2v av = __builtin_bit_cast(half2v, a);
    half2v wv = __builtin_bit_cast(half2v, w);
    c = fmaf((float)av.x, (float)wv.x, c);
    return fmaf((float)av.y, (float)wv.y, c);
#endif
}

__device__ __forceinline__ uint32 pkh(float a, float b)
{
    __half ha = __float2half(a), hb = __float2half(b);
    ushort ua = *reinterpret_cast<ushort*>(&ha);
    ushort ub = *reinterpret_cast<ushort*>(&hb);
    return (uint32)ua | ((uint32)ub << 16);
}

// Member g's cat slice, k_slice in [0,448):
//  [0,256) -> x cols 256g+k ; [256,384) -> s cols 128g+(k-256) ; [384,448) -> I cols 64g+(k-384)
__device__ __forceinline__ float getSlice(const float* __restrict__ W_ih,
                                          const float* __restrict__ W_hh,
                                          int g, int j, int k)
{
    if (k < 256) return W_ih[j * 640 + 256 * g + k];
    if (k < 384) return W_hh[j * 256 + 128 * g + (k - 256)];
    return W_ih[j * 640 + 512 + 64 * g + (k - 384)];
}

// Per-thread weight layout: identical to rounds 10/11 (proven absmax 0.0039).
__global__ void prep_kernel(const float* __restrict__ W_ih,
                            const float* __restrict__ W_hh,
                            const float* __restrict__ W_out,
                            uint32* __restrict__ WREGH,
                            uint64* __restrict__ zbase)
{
    int idx = blockIdx.x * blockDim.x + threadIdx.x;
    if (idx < WREG_N) {
        int tid  = idx & 511;
        int q    = idx >> 9;       // g*176 + slot
        int g    = q / 176;
        int slot = q % 176;
        float lo, hi;
        if (slot < 112) {
            int j = tid >> 1, h = tid & 1;
            int k0 = 2 * (112 * h + slot);
            lo = getSlice(W_ih, W_hh, g, j, k0);
            hi = getSlice(W_ih, W_hh, g, j, k0 + 1);
        } else {
            int s  = slot - 112;
            int ii = s >> 2, m = s & 3;
            int nloc = tid >> 1, hh = tid & 1;
            int n  = 256 * g + nloc;
            int k0 = 128 * hh + 8 * ii + 2 * m;
            lo = W_out[n * 256 + k0];
            hi = W_out[n * 256 + k0 + 1];
        }
        WREGH[idx] = pkh(lo, hi);
    } else if (idx < WREG_N + ZQ_N) {
        zbase[idx - WREG_N] = 0ULL;   // exchange tags + pairing state start 0
    }
}

// LDS-only barrier: does NOT drain vmcnt (global ops stay in flight).
__device__ __forceinline__ void bar_lds()
{
    asm volatile("s_waitcnt lgkmcnt(0)" ::: "memory");
    __builtin_amdgcn_s_barrier();
    asm volatile("" ::: "memory");
}

// ---- atomic-RMW L2 channel: RMWs execute at the issuing CU's TCC, bypassing
// L1. Same-XCD pairs share a TCC -> coherent at L2 latency. Cross-XCD pairs
// RMW different TCCs -> never coherent -> bounded probe fails -> fallback. ----
__device__ __forceinline__ void atom_sw64(uint64* p, uint64 v)
{
    asm volatile("global_atomic_swap_x2 %0, %1, off" :: "v"(p), "v"(v) : "memory");
}
__device__ __forceinline__ uint64 atom_rd64(uint64* p)   // atomic add 0, return old
{
    uint64 r;
    uint64 z = 0;
    asm volatile("global_atomic_add_x2 %0, %1, %2, off sc0\n\ts_waitcnt vmcnt(0)"
                 : "=&v"(r) : "v"(p), "v"(z) : "memory");
    return r;
}
__device__ __forceinline__ void atom_sw32(uint32* p, uint32 v)
{
    asm volatile("global_atomic_swap %0, %1, off" :: "v"(p), "v"(v) : "memory");
}
__device__ __forceinline__ uint32 atom_rd32(uint32* p)
{
    uint32 r;
    uint32 z = 0;
    asm volatile("global_atomic_add %0, %1, %2, off sc0\n\ts_waitcnt vmcnt(0)"
                 : "=&v"(r) : "v"(p), "v"(z) : "memory");
    return r;
}

__global__ __launch_bounds__(512, 2)
void scan_kernel(const float* __restrict__ I,
                 const float* __restrict__ b_ih, const float* __restrict__ b_hh,
                 const float* __restrict__ b_out, const float* __restrict__ A,
                 const uint32* __restrict__ WREGH,
                 uint64* exS, uint64* exF, uint32* PS,
                 float* __restrict__ out)
{
    __shared__ uint4 apk4[2][56];     // member-slice act, fp16 pairs, dbuf
    __shared__ uint4 s4pk[34];        // FULL s packed pairs, PADDED (17-stride
                                      //  kills the 256B same-bank conflict)
    __shared__ float xf32[256];       // exact f32 x state (own n-half)
    __shared__ uint32 shInfo[2];      // {e | g<<16, fastpair}

    const int tid = threadIdx.x;

    // ---------- dynamic same-XCD pairing + ATOMIC-channel validation ----------
    if (tid == 0) {
        uint32 x;
        asm volatile("s_getreg_b32 %0, hwreg(HW_REG_XCC_ID)" : "=s"(x));
        x &= 7u;   // clamp: garbage reads degrade to fallback, never fault
        uint32 rank = __hip_atomic_fetch_add(PS + x, 1u,
                          __ATOMIC_RELAXED, __HIP_MEMORY_SCOPE_AGENT);
        __hip_atomic_fetch_add(PS + 8, 1u, __ATOMIC_RELAXED, __HIP_MEMORY_SCOPE_AGENT);
        // all 128 WGs co-resident; every WG adds unconditionally -> live wait
        while (__hip_atomic_load(PS + 8, __ATOMIC_RELAXED, __HIP_MEMORY_SCOPE_AGENT) < 128u)
            __builtin_amdgcn_s_sleep(1);
        uint32 cnt[8];
        #pragma unroll
        for (int i = 0; i < 8; ++i)
            cnt[i] = __hip_atomic_load(PS + i, __ATOMIC_RELAXED, __HIP_MEMORY_SCOPE_AGENT);
        uint32 totp = 0, cumB = 0, sB = 0;
        #pragma unroll
        for (int i = 0; i < 8; ++i) {
            if ((uint32)i < x) { cumB += cnt[i] >> 1; sB += cnt[i] & 1; }
            totp += cnt[i] >> 1;
        }
        uint32 e, g;
        if (rank < 2u * (cnt[x] >> 1)) { e = cumB + (rank >> 1); g = rank & 1u; }
        else                           { e = totp + (sB >> 1);   g = sB & 1u; }
        // bounded ATOMIC probe of THIS pair's channel; vote on live agent channel
        uint32* pb = PS + 16  + 2 * e;
        uint32* vt = PS + 160 + 2 * e;
        const uint32 TOK = 0x5EEDF00Du;
        atom_sw32(pb + g, TOK);
        uint32 seen = 0;
        for (int it = 0; it < 512 && !seen; ++it)
            seen = (atom_rd32(pb + (1u - g)) == TOK) ? 1u : 0u;
        __hip_atomic_store(vt + g, seen ? 2u : 1u,
                           __ATOMIC_RELAXED, __HIP_MEMORY_SCOPE_AGENT);
        uint32 v0, v1;
        do {
            v0 = __hip_atomic_load(vt + 0, __ATOMIC_RELAXED, __HIP_MEMORY_SCOPE_AGENT);
            v1 = __hip_atomic_load(vt + 1, __ATOMIC_RELAXED, __HIP_MEMORY_SCOPE_AGENT);
        } while (v0 == 0u || v1 == 0u);
        shInfo[0] = e | (g << 16);
        shInfo[1] = (v0 == 2u && v1 == 2u) ? 1u : 0u;
    }
    __syncthreads();
    const int  e        = shInfo[0] & 0xffff;
    const int  g        = shInfo[0] >> 16;
    const bool fastpair = (shInfo[1] != 0);
    bool fastok = fastpair;            // sticky per-thread poll-side switch

    // ---- weights -> VGPR (static-indexed, fully unrolled, pinned) ----
    uint32 wA[112], wB[64];
    const uint32* wsrc = WREGH + (size_t)g * (176 * 512) + tid;
    #pragma unroll
    for (int i = 0; i < 112; ++i) { wA[i] = wsrc[(size_t)i * 512]; asm("" : "+v"(wA[i])); }
    #pragma unroll
    for (int i = 0; i < 64;  ++i) { wB[i] = wsrc[(size_t)(112 + i) * 512]; asm("" : "+v"(wB[i])); }

    const int h    = tid & 1;     // A k-half within lane pair (224 k each)
    const int jA   = tid >> 1;    // A output row [0,256)
    const int hh   = tid & 1;     // B k-half (128 k each)
    const int nloc = tid >> 1;    // B output row within member half

    const float bs   = ((tid & 1) == 0) ? (b_ih[jA] + b_hh[jA]) : 0.f;
    const float bo_r = ((tid & 1) == 0) ? b_out[256 * g + nloc] : 0.f;
    const float Av_r = ((tid & 1) == 0) ? A[256 * g + nloc] : 0.f;

    const size_t iBase   = (size_t)e * TT * 128 + 64 * g;
    const size_t outBase = (size_t)e * TT * 512 + 256 * g;

    {   // init buffer 0: x=0 (pairs 0..127), s=0 (128..191), I(0) (192..223)
        uint32* a0p = (uint32*)&apk4[0][0];
        if (tid < 192) a0p[tid] = 0u;
        else if (tid < 224) {
            int m = tid - 192;
            a0p[tid] = pkh(I[iBase + 2 * m], I[iBase + 2 * m + 1]);
        }
        if (tid < 256) xf32[tid] = 0.f;
    }
    __syncthreads();

    for (int t = 0; t < TT; ++t) {
        const int par = t & 1;
        const uint4* rdp = apk4[par];
        uint32*      wrp = (uint32*)apk4[par ^ 1];

        // I(t+1): issue loads early (hides HBM under compute + sync)
        float2 iv2 = make_float2(0.f, 0.f);
        if (tid < 32) {
            int tl = (t + 1 < TT) ? (t + 1) : t;
            iv2 = *(const float2*)(I + iBase + (size_t)tl * 128 + 2 * tid);
        }

        // ---- phase A: pre[jA] partial over this member's 448-k slice ----
        float a0 = 0.f, a1 = 0.f, a2 = 0.f, a3 = 0.f;   // 4 accs: break dep chain
        #pragma unroll
        for (int i = 0; i < 28; ++i) {
            uint4 av = rdp[28 * h + i];      // 2 addrs/wave -> LDS broadcast
            a0 = dot2(av.x, wA[4 * i + 0], a0);
            a1 = dot2(av.y, wA[4 * i + 1], a1);
            a2 = dot2(av.z, wA[4 * i + 2], a2);
            a3 = dot2(av.w, wA[4 * i + 3], a3);
        }
        float acc = (a0 + a1) + (a2 + a3);
        acc += __shfl_xor(acc, 1);           // h0 + h1 -> full slice partial

        const uint32 tgt   = (uint32)(t + 1);
        const size_t exoff = (size_t)(par * 64 + e) * (2 * 256);

        float sn = 0.f;
        if ((tid & 1) == 0) {
            uint64 u = ((uint64)tgt << 32) | (uint64)__float_as_uint(acc);
            // dup-store: fast atomic (shared TCC) if validated; agent copy ALWAYS
            if (fastpair) atom_sw64(exF + exoff + g * 256 + jA, u);
            __hip_atomic_store(exS + exoff + g * 256 + jA, u,
                               __ATOMIC_RELAXED, __HIP_MEMORY_SCOPE_AGENT);

            uint64* fp = exF + exoff + (1 - g) * 256 + jA;
            uint64* sp = exS + exoff + (1 - g) * 256 + jA;
            uint64 up = 0; bool got = false;
            if (fastok) {                    // bounded L2-atomic poll; sticky fallback
                for (int it = 0; it < 4096 && !got; ++it) {
                    up = atom_rd64(fp);
                    got = ((uint32)(up >> 32) == tgt);
                }
                if (!got) fastok = false;
            }
            while (!got) {                   // proven-live agent channel
                up = __hip_atomic_load(sp, __ATOMIC_RELAXED, __HIP_MEMORY_SCOPE_AGENT);
                got = ((uint32)(up >> 32) == tgt);
            }

            float pre = acc + bs + __uint_as_float((uint32)up);  // fixed order
            // tanh(x) = 1 - 2/(exp(2x)+1): exact identity, branch-free
            float ex2 = __expf(2.f * pre);
            sn = 1.f - 2.f / (ex2 + 1.f);
        }
        {   // pack s pairs: threads 4m (jA=2m) and 4m+2 (jA=2m+1)
            float sno = __shfl_xor(sn, 2);
            if ((tid & 3) == 0) {
                int p = tid >> 2;                    // full-s pair index [0,128)
                uint32 sp2 = pkh(sn, sno);
                ((uint32*)s4pk)[p < 64 ? p : p + 4] = sp2;   // padded layout
                int d = p - 64 * g;                  // own s-half for next A
                if (d >= 0 && d < 64) wrp[128 + d] = sp2;
            }
        }
        bar_lds();                           // (1) s ready

        // ---- phase B: f[n], lane pair covers k=256 (padded: banks disjoint) ----
        float c0 = 0.f, c1 = 0.f, c2 = 0.f, c3 = 0.f;
        #pragma unroll
        for (int i = 0; i < 16; ++i) {
            uint4 sv = s4pk[17 * hh + i];    // 2 addrs/wave, different banks now
            c0 = dot2(sv.x, wB[4 * i + 0], c0);
            c1 = dot2(sv.y, wB[4 * i + 1], c1);
            c2 = dot2(sv.z, wB[4 * i + 2], c2);
            c3 = dot2(sv.w, wB[4 * i + 3], c3);
        }
        float f = (c0 + c1) + (c2 + c3);
        f += __shfl_xor(f, 1);               // full k-sum at both pair lanes

        float xn = 0.f;
        if ((tid & 1) == 0) {
            float ff = fmaxf(f + bo_r, 0.f);
            float xo = xf32[nloc];           // exact f32 state in, f32 out
            xn = (xo + 0.1f * ff * Av_r) / (1.1f + 0.1f * ff);
            xf32[nloc] = xn;                 // same-thread RMW: no race
            out[outBase + (size_t)t * 512 + nloc] = xn;
        }
        {   // pack x pairs (fp16 copy feeds next A): threads 4m / 4m+2
            float xno = __shfl_xor(xn, 2);
            if ((tid & 3) == 0)
                wrp[tid >> 2] = pkh(xn, xno);
        }
        if (tid < 32) wrp[192 + tid] = pkh(iv2.x, iv2.y);   // stage I(t+1)
        bar_lds();                           // (2) state ready for next A
    }
}

extern "C" void kernel_launch(void* const* d_in, const int* in_sizes, int n_in,
                              void* d_out, int out_size, void* d_ws, size_t ws_size,
                              hipStream_t stream)
{
    const float* I     = (const float*)d_in[0];
    const float* W_ih  = (const float*)d_in[1];
    const float* W_hh  = (const float*)d_in[2];
    const float* b_ih  = (const float*)d_in[3];
    const float* b_hh  = (const float*)d_in[4];
    const float* W_out = (const float*)d_in[5];
    const float* b_out = (const float*)d_in[6];
    const float* A     = (const float*)d_in[7];

    uint32* WREGH = (uint32*)d_ws;
    uint64* zbase = (uint64*)((uint32*)d_ws + WREG_N);   // exS | exF | PS
    uint64* exS   = zbase;
    uint64* exF   = zbase + EX_N;
    uint32* PS    = (uint32*)(zbase + 2 * EX_N);

    const int total = WREG_N + ZQ_N;
    prep_kernel<<<(total + 1023) / 1024, 1024, 0, stream>>>(W_ih, W_hh, W_out,
                                                            WREGH, zbase);
    scan_kernel<<<128, 512, 0, stream>>>(I, b_ih, b_hh, b_out, A,
                                         WREGH, exS, exF, PS, (float*)d_out);
}